// Round 1
// baseline (552.753 us; speedup 1.0000x reference)
//
#include <hip/hip_runtime.h>
#include <stdint.h>

#define NNODES 50000
#define NEDGES 800000
#define CDIM   64
#define SHD    9
#define EBD    16

using f32x4  = __attribute__((ext_vector_type(4))) float;
using bf16x8 = __attribute__((ext_vector_type(8))) __bf16;

static __device__ __forceinline__ unsigned short f2bf(float x) {
  union { float f; unsigned u; } v; v.f = x;
  unsigned r = (v.u + 0x7FFFu + ((v.u >> 16) & 1u)) >> 16;   // RNE
  return (unsigned short)r;
}
static __device__ __forceinline__ float bf2f(unsigned short b) {
  union { unsigned u; float f; } v; v.u = ((unsigned)b) << 16;
  return v.f;
}
static __device__ __forceinline__ f32x4 mfma16(bf16x8 a, bf16x8 b, f32x4 c) {
  return __builtin_amdgcn_mfma_f32_16x16x32_bf16(a, b, c, 0, 0, 0);
}

// Pack fp32 weight w[K][N] (row-major) into bf16 B-fragment order for
// mfma_f32_16x16x32_bf16: dst[((nt*KS+ks)*64 + lane)*8 + j] =
//   w[ks*32 + (lane>>4)*8 + j][nt*16 + (lane&15)], zero-padded OOB.
__global__ void pack_w_kernel(const float* __restrict__ w, unsigned short* __restrict__ dst,
                              int K, int N, int KS, int NT) {
  int idx = blockIdx.x * 256 + threadIdx.x;
  int total = NT * KS * 64;
  if (idx >= total) return;
  int lane = idx & 63;
  int t = idx >> 6;
  int ks = t % KS;
  int nt = t / KS;
  int n  = nt * 16 + (lane & 15);
  int kb = ks * 32 + ((lane >> 4) << 3);
  unsigned short v[8];
#pragma unroll
  for (int j = 0; j < 8; ++j) {
    int k = kb + j;
    float val = (k < K && n < N) ? w[(size_t)k * N + n] : 0.f;
    v[j] = f2bf(val);
  }
  uint4 pk;
  pk.x = (unsigned)v[0] | ((unsigned)v[1] << 16);
  pk.y = (unsigned)v[2] | ((unsigned)v[3] << 16);
  pk.z = (unsigned)v[4] | ((unsigned)v[5] << 16);
  pk.w = (unsigned)v[6] | ((unsigned)v[7] << 16);
  reinterpret_cast<uint4*>(dst)[idx] = pk;
}

// Fused per-edge pipeline. 64 edges per block, 256 threads (4 waves).
__global__ __launch_bounds__(256, 2) void edge_kernel(
    const float* __restrict__ hn, const float* __restrict__ he,
    const float* __restrict__ fe, const float* __restrict__ fes,
    const float* __restrict__ nrm,
    const int* __restrict__ esrc, const int* __restrict__ edst,
    const unsigned short* __restrict__ pev1, const float* __restrict__ bev1,
    const unsigned short* __restrict__ pev2, const float* __restrict__ bev2,
    const unsigned short* __restrict__ ptp,  const float* __restrict__ btp,
    const unsigned short* __restrict__ peu1, const float* __restrict__ beu1,
    const unsigned short* __restrict__ peu2, const float* __restrict__ beu2,
    float* __restrict__ out_he, float* __restrict__ nf) {
  __shared__ unsigned short xa[64][200];   // [he | hs | hd] bf16, pad +8 (2-way banks only)
  __shared__ unsigned short xt[64][72];    // [v | fe | fes | 0] K-padded to 64
  __shared__ unsigned short tb[64][72];    // t
  __shared__ unsigned short act[64][264];  // hidden activations (a1 then a2)

  const int tid  = threadIdx.x;
  const int lane = tid & 63;
  const int wid  = tid >> 6;
  const int eb   = blockIdx.x * 64;
  const int arow = lane & 15;
  const int koff = (lane >> 4) << 3;
  const int r0   = (lane >> 4) << 2;

  // ---- stage inputs ----
  {
    const int e  = tid >> 2;
    const int q  = tid & 3;
    const int cg = q << 4;
    const int eg = eb + e;
    const int src = esrc[eg];
    const int dst = edst[eg];
    const float4* heP = reinterpret_cast<const float4*>(he + (size_t)eg * 64 + cg);
    const float4* hsP = reinterpret_cast<const float4*>(hn + (size_t)src * 64 + cg);
    const float4* hdP = reinterpret_cast<const float4*>(hn + (size_t)dst * 64 + cg);
#pragma unroll
    for (int i = 0; i < 4; ++i) {
      float4 a = heP[i], b = hsP[i], d = hdP[i];
      *reinterpret_cast<ushort4*>(&xa[e][cg + i * 4]) =
          make_ushort4(f2bf(a.x), f2bf(a.y), f2bf(a.z), f2bf(a.w));
      *reinterpret_cast<ushort4*>(&xa[e][64 + cg + i * 4]) =
          make_ushort4(f2bf(b.x), f2bf(b.y), f2bf(b.z), f2bf(b.w));
      *reinterpret_cast<ushort4*>(&xa[e][128 + cg + i * 4]) =
          make_ushort4(f2bf(d.x), f2bf(d.y), f2bf(d.z), f2bf(d.w));
    }
    // xt: cols 9..17 = fe, 18..33 = fes, 34..63 = 0 (cols 0..8 = v, filled later)
#pragma unroll
    for (int i = 0; i < 16; ++i) {
      int col = cg + i;
      if (col < 9) continue;
      float v = 0.f;
      if (col < 18)      v = fe[(size_t)eg * SHD + (col - 9)];
      else if (col < 34) v = fes[(size_t)eg * EBD + (col - 18)];
      xt[e][col] = f2bf(v);
    }
  }
  __syncthreads();

  // ---- GEMM1: a1 = relu([he|hs|hd] @ w_ev1 + b_ev1); wave owns N-slice [wid*64, wid*64+64) ----
  {
    f32x4 acc[4][4];
#pragma unroll
    for (int m = 0; m < 4; ++m)
#pragma unroll
      for (int n = 0; n < 4; ++n) acc[m][n] = (f32x4){0.f, 0.f, 0.f, 0.f};
#pragma unroll
    for (int ks = 0; ks < 6; ++ks) {
      bf16x8 a[4];
#pragma unroll
      for (int m = 0; m < 4; ++m)
        a[m] = *reinterpret_cast<const bf16x8*>(&xa[m * 16 + arow][ks * 32 + koff]);
#pragma unroll
      for (int n = 0; n < 4; ++n) {
        bf16x8 b = *reinterpret_cast<const bf16x8*>(
            pev1 + (((size_t)(wid * 4 + n) * 6 + ks) * 64 + lane) * 8);
#pragma unroll
        for (int m = 0; m < 4; ++m) acc[m][n] = mfma16(a[m], b, acc[m][n]);
      }
    }
#pragma unroll
    for (int n = 0; n < 4; ++n) {
      const int col = wid * 64 + n * 16 + arow;
      const float bias = bev1[col];
#pragma unroll
      for (int m = 0; m < 4; ++m)
#pragma unroll
        for (int r = 0; r < 4; ++r) {
          float v = acc[m][n][r] + bias;
          act[m * 16 + r0 + r][col] = f2bf(v > 0.f ? v : 0.f);
        }
    }
  }
  __syncthreads();

  // ---- GEMM2: v = a1 @ w_ev2 + b_ev2 (N=9 padded to 16); wave owns M-tile wid ----
  {
    f32x4 acc = (f32x4){0.f, 0.f, 0.f, 0.f};
    const int mrow = wid * 16 + arow;
#pragma unroll
    for (int ks = 0; ks < 8; ++ks) {
      bf16x8 a = *reinterpret_cast<const bf16x8*>(&act[mrow][ks * 32 + koff]);
      bf16x8 b = *reinterpret_cast<const bf16x8*>(pev2 + ((size_t)ks * 64 + lane) * 8);
      acc = mfma16(a, b, acc);
    }
    if (arow < 9) {
      const float bias = bev2[arow];
#pragma unroll
      for (int r = 0; r < 4; ++r) xt[wid * 16 + r0 + r][arow] = f2bf(acc[r] + bias);
    }
  }
  __syncthreads();

  // ---- GEMM_t: t = [v|fe|fes] @ w_tp + b_tp (K padded 34->64); wave owns M-tile ----
  {
    f32x4 acc[4];
#pragma unroll
    for (int n = 0; n < 4; ++n) acc[n] = (f32x4){0.f, 0.f, 0.f, 0.f};
    const int mrow = wid * 16 + arow;
#pragma unroll
    for (int ks = 0; ks < 2; ++ks) {
      bf16x8 a = *reinterpret_cast<const bf16x8*>(&xt[mrow][ks * 32 + koff]);
#pragma unroll
      for (int n = 0; n < 4; ++n) {
        bf16x8 b = *reinterpret_cast<const bf16x8*>(ptp + (((size_t)n * 2 + ks) * 64 + lane) * 8);
        acc[n] = mfma16(a, b, acc[n]);
      }
    }
#pragma unroll
    for (int n = 0; n < 4; ++n) {
      const int col = n * 16 + arow;
      const float bias = btp[col];
#pragma unroll
      for (int r = 0; r < 4; ++r) tb[wid * 16 + r0 + r][col] = f2bf(acc[n][r] + bias);
    }
  }
  __syncthreads();

  // ---- GEMM3: a2 = relu([t|hs|hd] @ w_eu1 + b_eu1); wave owns N-slice ----
  {
    f32x4 acc[4][4];
#pragma unroll
    for (int m = 0; m < 4; ++m)
#pragma unroll
      for (int n = 0; n < 4; ++n) acc[m][n] = (f32x4){0.f, 0.f, 0.f, 0.f};
#pragma unroll
    for (int ks = 0; ks < 6; ++ks) {
      bf16x8 a[4];
#pragma unroll
      for (int m = 0; m < 4; ++m) {
        if (ks < 2)
          a[m] = *reinterpret_cast<const bf16x8*>(&tb[m * 16 + arow][ks * 32 + koff]);
        else
          a[m] = *reinterpret_cast<const bf16x8*>(&xa[m * 16 + arow][64 + (ks - 2) * 32 + koff]);
      }
#pragma unroll
      for (int n = 0; n < 4; ++n) {
        bf16x8 b = *reinterpret_cast<const bf16x8*>(
            peu1 + (((size_t)(wid * 4 + n) * 6 + ks) * 64 + lane) * 8);
#pragma unroll
        for (int m = 0; m < 4; ++m) acc[m][n] = mfma16(a[m], b, acc[m][n]);
      }
    }
#pragma unroll
    for (int n = 0; n < 4; ++n) {
      const int col = wid * 64 + n * 16 + arow;
      const float bias = beu1[col];
#pragma unroll
      for (int m = 0; m < 4; ++m)
#pragma unroll
        for (int r = 0; r < 4; ++r) {
          float v = acc[m][n][r] + bias;
          act[m * 16 + r0 + r][col] = f2bf(v > 0.f ? v : 0.f);
        }
    }
  }
  __syncthreads();

  // ---- GEMM4: he_new = he + a2 @ w_eu2 + b_eu2; write out + atomic scatter ----
  {
    f32x4 acc[4];
#pragma unroll
    for (int n = 0; n < 4; ++n) acc[n] = (f32x4){0.f, 0.f, 0.f, 0.f};
    const int mrow = wid * 16 + arow;
#pragma unroll
    for (int ks = 0; ks < 8; ++ks) {
      bf16x8 a = *reinterpret_cast<const bf16x8*>(&act[mrow][ks * 32 + koff]);
#pragma unroll
      for (int n = 0; n < 4; ++n) {
        bf16x8 b = *reinterpret_cast<const bf16x8*>(peu2 + (((size_t)n * 8 + ks) * 64 + lane) * 8);
        acc[n] = mfma16(a, b, acc[n]);
      }
    }
#pragma unroll
    for (int r = 0; r < 4; ++r) {
      const int erow = wid * 16 + r0 + r;
      const int eg = eb + erow;
      const float nv = nrm[eg];
      const int dn = edst[eg];
#pragma unroll
      for (int n = 0; n < 4; ++n) {
        const int col = n * 16 + arow;
        float v = acc[n][r] + beu2[col] + bf2f(xa[erow][col]);
        out_he[(size_t)eg * 64 + col] = v;
        atomicAdd(nf + (size_t)dn * 64 + col, v * nv);
      }
    }
  }
}

// Node MLP: hn_new = hn + relu([hn|node_ftr]@w_nl1+b)@w_nl2+b
__global__ __launch_bounds__(256, 2) void node_kernel(
    const float* __restrict__ hn, const float* __restrict__ nf,
    const unsigned short* __restrict__ pnl1, const float* __restrict__ bnl1,
    const unsigned short* __restrict__ pnl2, const float* __restrict__ bnl2,
    float* __restrict__ out) {
  __shared__ unsigned short xn[64][136];   // [hn | node_ftr]
  __shared__ unsigned short act[64][264];
  const int tid = threadIdx.x, lane = tid & 63, wid = tid >> 6;
  const int nb = blockIdx.x * 64;
  const int arow = lane & 15, koff = (lane >> 4) << 3, r0 = (lane >> 4) << 2;
  {
    const int rrow = tid >> 2, q = tid & 3, cg = q << 4;
    const int g = nb + rrow;
    if (g < NNODES) {
      const float4* aP = reinterpret_cast<const float4*>(hn + (size_t)g * 64 + cg);
      const float4* bP = reinterpret_cast<const float4*>(nf + (size_t)g * 64 + cg);
#pragma unroll
      for (int i = 0; i < 4; ++i) {
        float4 a = aP[i], b = bP[i];
        *reinterpret_cast<ushort4*>(&xn[rrow][cg + i * 4]) =
            make_ushort4(f2bf(a.x), f2bf(a.y), f2bf(a.z), f2bf(a.w));
        *reinterpret_cast<ushort4*>(&xn[rrow][64 + cg + i * 4]) =
            make_ushort4(f2bf(b.x), f2bf(b.y), f2bf(b.z), f2bf(b.w));
      }
    } else {
      ushort4 z = make_ushort4(0, 0, 0, 0);
#pragma unroll
      for (int i = 0; i < 4; ++i) {
        *reinterpret_cast<ushort4*>(&xn[rrow][cg + i * 4]) = z;
        *reinterpret_cast<ushort4*>(&xn[rrow][64 + cg + i * 4]) = z;
      }
    }
  }
  __syncthreads();
  {
    f32x4 acc[4][4];
#pragma unroll
    for (int m = 0; m < 4; ++m)
#pragma unroll
      for (int n = 0; n < 4; ++n) acc[m][n] = (f32x4){0.f, 0.f, 0.f, 0.f};
#pragma unroll
    for (int ks = 0; ks < 4; ++ks) {
      bf16x8 a[4];
#pragma unroll
      for (int m = 0; m < 4; ++m)
        a[m] = *reinterpret_cast<const bf16x8*>(&xn[m * 16 + arow][ks * 32 + koff]);
#pragma unroll
      for (int n = 0; n < 4; ++n) {
        bf16x8 b = *reinterpret_cast<const bf16x8*>(
            pnl1 + (((size_t)(wid * 4 + n) * 4 + ks) * 64 + lane) * 8);
#pragma unroll
        for (int m = 0; m < 4; ++m) acc[m][n] = mfma16(a[m], b, acc[m][n]);
      }
    }
#pragma unroll
    for (int n = 0; n < 4; ++n) {
      const int col = wid * 64 + n * 16 + arow;
      const float bias = bnl1[col];
#pragma unroll
      for (int m = 0; m < 4; ++m)
#pragma unroll
        for (int r = 0; r < 4; ++r) {
          float v = acc[m][n][r] + bias;
          act[m * 16 + r0 + r][col] = f2bf(v > 0.f ? v : 0.f);
        }
    }
  }
  __syncthreads();
  {
    f32x4 acc[4];
#pragma unroll
    for (int n = 0; n < 4; ++n) acc[n] = (f32x4){0.f, 0.f, 0.f, 0.f};
    const int mrow = wid * 16 + arow;
#pragma unroll
    for (int ks = 0; ks < 8; ++ks) {
      bf16x8 a = *reinterpret_cast<const bf16x8*>(&act[mrow][ks * 32 + koff]);
#pragma unroll
      for (int n = 0; n < 4; ++n) {
        bf16x8 b = *reinterpret_cast<const bf16x8*>(pnl2 + (((size_t)n * 8 + ks) * 64 + lane) * 8);
        acc[n] = mfma16(a, b, acc[n]);
      }
    }
#pragma unroll
    for (int r = 0; r < 4; ++r) {
      const int row = wid * 16 + r0 + r;
      const int g = nb + row;
      if (g < NNODES) {
#pragma unroll
        for (int n = 0; n < 4; ++n) {
          const int col = n * 16 + arow;
          out[(size_t)g * 64 + col] = bf2f(xn[row][col]) + acc[n][r] + bnl2[col];
        }
      }
    }
  }
}

extern "C" void kernel_launch(void* const* d_in, const int* in_sizes, int n_in,
                              void* d_out, int out_size, void* d_ws, size_t ws_size,
                              hipStream_t stream) {
  const float* hn   = (const float*)d_in[0];
  const float* he   = (const float*)d_in[1];
  const float* fe   = (const float*)d_in[2];
  const float* fes  = (const float*)d_in[3];
  const float* nrm  = (const float*)d_in[4];
  const int*   esrc = (const int*)d_in[5];
  const int*   edst = (const int*)d_in[6];
  const float* w_ev1 = (const float*)d_in[7];  const float* b_ev1 = (const float*)d_in[8];
  const float* w_ev2 = (const float*)d_in[9];  const float* b_ev2 = (const float*)d_in[10];
  const float* w_tp  = (const float*)d_in[11]; const float* b_tp  = (const float*)d_in[12];
  const float* w_eu1 = (const float*)d_in[13]; const float* b_eu1 = (const float*)d_in[14];
  const float* w_eu2 = (const float*)d_in[15]; const float* b_eu2 = (const float*)d_in[16];
  const float* w_nl1 = (const float*)d_in[17]; const float* b_nl1 = (const float*)d_in[18];
  const float* w_nl2 = (const float*)d_in[19]; const float* b_nl2 = (const float*)d_in[20];

  float* out = (float*)d_out;
  char* ws = (char*)d_ws;
  float* nf = (float*)ws;                                   // node_ftr accumulator [N,64] f32
  size_t off = (size_t)NNODES * CDIM * sizeof(float);
  unsigned short* pev1 = (unsigned short*)(ws + off); off += (size_t)16 * 6 * 512 * 2;
  unsigned short* peu1 = (unsigned short*)(ws + off); off += (size_t)16 * 6 * 512 * 2;
  unsigned short* pev2 = (unsigned short*)(ws + off); off += (size_t)1 * 8 * 512 * 2;
  unsigned short* peu2 = (unsigned short*)(ws + off); off += (size_t)4 * 8 * 512 * 2;
  unsigned short* ptp  = (unsigned short*)(ws + off); off += (size_t)4 * 2 * 512 * 2;
  unsigned short* pnl1 = (unsigned short*)(ws + off); off += (size_t)16 * 4 * 512 * 2;
  unsigned short* pnl2 = (unsigned short*)(ws + off); off += (size_t)4 * 8 * 512 * 2;

  hipMemsetAsync(nf, 0, (size_t)NNODES * CDIM * sizeof(float), stream);

  auto pk = [&](const float* w, unsigned short* dst, int K, int N, int KS, int NT) {
    int total = NT * KS * 64;
    pack_w_kernel<<<(total + 255) / 256, 256, 0, stream>>>(w, dst, K, N, KS, NT);
  };
  pk(w_ev1, pev1, 192, 256, 6, 16);
  pk(w_eu1, peu1, 192, 256, 6, 16);
  pk(w_ev2, pev2, 256, 9, 8, 1);
  pk(w_eu2, peu2, 256, 64, 8, 4);
  pk(w_tp,  ptp,  34, 64, 2, 4);
  pk(w_nl1, pnl1, 128, 256, 4, 16);
  pk(w_nl2, pnl2, 256, 64, 8, 4);

  edge_kernel<<<NEDGES / 64, 256, 0, stream>>>(
      hn, he, fe, fes, nrm, esrc, edst,
      pev1, b_ev1, pev2, b_ev2, ptp, b_tp, peu1, b_eu1, peu2, b_eu2,
      out + (size_t)NNODES * CDIM, nf);

  node_kernel<<<(NNODES + 63) / 64, 256, 0, stream>>>(
      hn, nf, pnl1, b_nl1, pnl2, b_nl2, out);
}

// Round 2
// 477.273 us; speedup vs baseline: 1.1581x; 1.1581x over previous
//
#include <hip/hip_runtime.h>
#include <stdint.h>

#define NNODES 50000
#define NEDGES 800000
#define CDIM   64
#define SHD    9
#define EBD    16

using f32x4  = __attribute__((ext_vector_type(4))) float;
using bf16x8 = __attribute__((ext_vector_type(8))) __bf16;

static __device__ __forceinline__ unsigned short f2bf(float x) {
  union { float f; unsigned u; } v; v.f = x;
  unsigned r = (v.u + 0x7FFFu + ((v.u >> 16) & 1u)) >> 16;   // RNE
  return (unsigned short)r;
}
static __device__ __forceinline__ float bf2f(unsigned short b) {
  union { unsigned u; float f; } v; v.u = ((unsigned)b) << 16;
  return v.f;
}
static __device__ __forceinline__ f32x4 mfma16(bf16x8 a, bf16x8 b, f32x4 c) {
  return __builtin_amdgcn_mfma_f32_16x16x32_bf16(a, b, c, 0, 0, 0);
}

// One merged pack kernel: fp32 w[K][N] row-major -> bf16 B-fragment order for
// mfma_f32_16x16x32_bf16: dst[((nt*KS+ks)*64 + lane)*8 + j] =
//   w[ks*32 + (lane>>4)*8 + j][nt*16 + (lane&15)], zero-padded OOB.
__global__ void pack_all_kernel(
    const float* __restrict__ wev1, const float* __restrict__ weu1,
    const float* __restrict__ wnl1, const float* __restrict__ weu2,
    const float* __restrict__ wnl2, const float* __restrict__ wev2,
    const float* __restrict__ wtp,
    unsigned short* __restrict__ pev1, unsigned short* __restrict__ peu1,
    unsigned short* __restrict__ pnl1, unsigned short* __restrict__ peu2,
    unsigned short* __restrict__ pnl2, unsigned short* __restrict__ pev2,
    unsigned short* __restrict__ ptp) {
  int b = blockIdx.x;
  const float* w; unsigned short* dst; int K, N, KS, NT, base;
  if (b < 24)      { w = wev1; dst = pev1; K = 192; N = 256; KS = 6; NT = 16; base = 0; }
  else if (b < 48) { w = weu1; dst = peu1; K = 192; N = 256; KS = 6; NT = 16; base = 24; }
  else if (b < 64) { w = wnl1; dst = pnl1; K = 128; N = 256; KS = 4; NT = 16; base = 48; }
  else if (b < 72) { w = weu2; dst = peu2; K = 256; N = 64;  KS = 8; NT = 4;  base = 64; }
  else if (b < 80) { w = wnl2; dst = pnl2; K = 256; N = 64;  KS = 8; NT = 4;  base = 72; }
  else if (b < 82) { w = wev2; dst = pev2; K = 256; N = 9;   KS = 8; NT = 1;  base = 80; }
  else             { w = wtp;  dst = ptp;  K = 34;  N = 64;  KS = 2; NT = 4;  base = 82; }
  int idx = (b - base) * 256 + threadIdx.x;
  int total = NT * KS * 64;
  if (idx >= total) return;
  int lane = idx & 63;
  int t = idx >> 6;
  int ks = t % KS;
  int nt = t / KS;
  int n  = nt * 16 + (lane & 15);
  int kb = ks * 32 + ((lane >> 4) << 3);
  unsigned short v[8];
#pragma unroll
  for (int j = 0; j < 8; ++j) {
    int k = kb + j;
    float val = (k < K && n < N) ? w[(size_t)k * N + n] : 0.f;
    v[j] = f2bf(val);
  }
  uint4 pk;
  pk.x = (unsigned)v[0] | ((unsigned)v[1] << 16);
  pk.y = (unsigned)v[2] | ((unsigned)v[3] << 16);
  pk.z = (unsigned)v[4] | ((unsigned)v[5] << 16);
  pk.w = (unsigned)v[6] | ((unsigned)v[7] << 16);
  reinterpret_cast<uint4*>(dst)[idx] = pk;
}

// Fused per-edge pipeline. 64 edges per block, 256 threads (4 waves).
// LDS 52,224 B -> 3 blocks/CU (12 waves/CU).
__global__ __launch_bounds__(256, 3) void edge_kernel(
    const float* __restrict__ hn, const float* __restrict__ he,
    const float* __restrict__ fe, const float* __restrict__ fes,
    const float* __restrict__ nrm,
    const int* __restrict__ esrc, const int* __restrict__ edst,
    const unsigned short* __restrict__ pev1, const float* __restrict__ bev1,
    const unsigned short* __restrict__ pev2, const float* __restrict__ bev2,
    const unsigned short* __restrict__ ptp,  const float* __restrict__ btp,
    const unsigned short* __restrict__ peu1, const float* __restrict__ beu1,
    const unsigned short* __restrict__ peu2, const float* __restrict__ beu2,
    float* __restrict__ out_he, float* __restrict__ nf) {
  __shared__ unsigned short xa[64][200];   // [he | hs | hd] bf16 (+8 pad, stride%32w=4 -> free 2-way)
  __shared__ unsigned short vt[64][72];    // [v | fe | fes | 0] K-padded to 64; reused for t
  __shared__ unsigned short act[64][136];  // hidden activations, ONE N-half (128 cols + pad)

  const int tid  = threadIdx.x;
  const int lane = tid & 63;
  const int wid  = tid >> 6;
  const int eb   = blockIdx.x * 64;
  const int arow = lane & 15;
  const int koff = (lane >> 4) << 3;
  const int r0   = (lane >> 4) << 2;

  // ---- stage inputs (wave w stages its own edges 16w..16w+15) ----
  {
    const int e  = tid >> 2;
    const int q  = tid & 3;
    const int cg = q << 4;
    const int eg = eb + e;
    const int src = esrc[eg];
    const int dst = edst[eg];
    const float4* heP = reinterpret_cast<const float4*>(he + (size_t)eg * 64 + cg);
    const float4* hsP = reinterpret_cast<const float4*>(hn + (size_t)src * 64 + cg);
    const float4* hdP = reinterpret_cast<const float4*>(hn + (size_t)dst * 64 + cg);
#pragma unroll
    for (int i = 0; i < 4; ++i) {
      float4 a = heP[i], b = hsP[i], d = hdP[i];
      *reinterpret_cast<ushort4*>(&xa[e][cg + i * 4]) =
          make_ushort4(f2bf(a.x), f2bf(a.y), f2bf(a.z), f2bf(a.w));
      *reinterpret_cast<ushort4*>(&xa[e][64 + cg + i * 4]) =
          make_ushort4(f2bf(b.x), f2bf(b.y), f2bf(b.z), f2bf(b.w));
      *reinterpret_cast<ushort4*>(&xa[e][128 + cg + i * 4]) =
          make_ushort4(f2bf(d.x), f2bf(d.y), f2bf(d.z), f2bf(d.w));
    }
    // vt: cols 9..17 = fe, 18..33 = fes, 34..63 = 0 (cols 0..8 = v, filled later)
#pragma unroll
    for (int i = 0; i < 16; ++i) {
      int col = cg + i;
      if (col < 9) continue;
      float v = 0.f;
      if (col < 18)      v = fe[(size_t)eg * SHD + (col - 9)];
      else if (col < 34) v = fes[(size_t)eg * EBD + (col - 18)];
      vt[e][col] = f2bf(v);
    }
  }
  __syncthreads();  // S1

  // ---- GEMM1 (two N-halves) interleaved with GEMM2 partial-K accumulation ----
  f32x4 acc2 = (f32x4){0.f, 0.f, 0.f, 0.f};
#pragma unroll
  for (int h = 0; h < 2; ++h) {
    {  // GEMM1 half: a1[:, h*128 : h*128+128] = relu([he|hs|hd] @ w_ev1 + b)
      f32x4 acc[4][2];
#pragma unroll
      for (int m = 0; m < 4; ++m)
#pragma unroll
        for (int n = 0; n < 2; ++n) acc[m][n] = (f32x4){0.f, 0.f, 0.f, 0.f};
#pragma unroll
      for (int ks = 0; ks < 6; ++ks) {
        bf16x8 a[4];
#pragma unroll
        for (int m = 0; m < 4; ++m)
          a[m] = *reinterpret_cast<const bf16x8*>(&xa[m * 16 + arow][ks * 32 + koff]);
#pragma unroll
        for (int n = 0; n < 2; ++n) {
          bf16x8 b = *reinterpret_cast<const bf16x8*>(
              pev1 + (((size_t)(h * 8 + wid * 2 + n) * 6 + ks) * 64 + lane) * 8);
#pragma unroll
          for (int m = 0; m < 4; ++m) acc[m][n] = mfma16(a[m], b, acc[m][n]);
        }
      }
#pragma unroll
      for (int n = 0; n < 2; ++n) {
        const int col_l = wid * 32 + n * 16 + arow;
        const float bias = bev1[h * 128 + col_l];
#pragma unroll
        for (int m = 0; m < 4; ++m)
#pragma unroll
          for (int r = 0; r < 4; ++r) {
            float v = acc[m][n][r] + bias;
            act[m * 16 + r0 + r][col_l] = f2bf(v > 0.f ? v : 0.f);
          }
      }
    }
    __syncthreads();  // S2 / S4
    {  // GEMM2 partial: acc2 += a1_half @ w_ev2_half
      const int mrow = wid * 16 + arow;
#pragma unroll
      for (int ksl = 0; ksl < 4; ++ksl) {
        bf16x8 a = *reinterpret_cast<const bf16x8*>(&act[mrow][ksl * 32 + koff]);
        bf16x8 b = *reinterpret_cast<const bf16x8*>(pev2 + (((size_t)h * 4 + ksl) * 64 + lane) * 8);
        acc2 = mfma16(a, b, acc2);
      }
    }
    if (h == 0) __syncthreads();  // S3 (before half-1 overwrites act)
  }

  // ---- v write (wave-private rows) + GEMM_t (within-wave; vt read-then-overwrite) ----
  if (arow < 9) {
    const float bias = bev2[arow];
#pragma unroll
    for (int r = 0; r < 4; ++r) vt[wid * 16 + r0 + r][arow] = f2bf(acc2[r] + bias);
  }
  {
    f32x4 acct[4];
#pragma unroll
    for (int n = 0; n < 4; ++n) acct[n] = (f32x4){0.f, 0.f, 0.f, 0.f};
    const int mrow = wid * 16 + arow;
#pragma unroll
    for (int ks = 0; ks < 2; ++ks) {
      bf16x8 a = *reinterpret_cast<const bf16x8*>(&vt[mrow][ks * 32 + koff]);
#pragma unroll
      for (int n = 0; n < 4; ++n) {
        bf16x8 b = *reinterpret_cast<const bf16x8*>(ptp + (((size_t)n * 2 + ks) * 64 + lane) * 8);
        acct[n] = mfma16(a, b, acct[n]);
      }
    }
#pragma unroll
    for (int n = 0; n < 4; ++n) {
      const int col = n * 16 + arow;
      const float bias = btp[col];
#pragma unroll
      for (int r = 0; r < 4; ++r) vt[wid * 16 + r0 + r][col] = f2bf(acct[n][r] + bias);
    }
  }
  __syncthreads();  // S5 (t visible to all waves)

  // ---- GEMM3 (two N-halves) interleaved with GEMM4 partial-K accumulation ----
  f32x4 acc4[4];
#pragma unroll
  for (int n = 0; n < 4; ++n) acc4[n] = (f32x4){0.f, 0.f, 0.f, 0.f};
#pragma unroll
  for (int h = 0; h < 2; ++h) {
    {  // GEMM3 half: a2[:, h*128 :] = relu([t|hs|hd] @ w_eu1 + b)
      f32x4 acc[4][2];
#pragma unroll
      for (int m = 0; m < 4; ++m)
#pragma unroll
        for (int n = 0; n < 2; ++n) acc[m][n] = (f32x4){0.f, 0.f, 0.f, 0.f};
#pragma unroll
      for (int ks = 0; ks < 6; ++ks) {
        bf16x8 a[4];
#pragma unroll
        for (int m = 0; m < 4; ++m) {
          if (ks < 2)
            a[m] = *reinterpret_cast<const bf16x8*>(&vt[m * 16 + arow][ks * 32 + koff]);
          else
            a[m] = *reinterpret_cast<const bf16x8*>(&xa[m * 16 + arow][64 + (ks - 2) * 32 + koff]);
        }
#pragma unroll
        for (int n = 0; n < 2; ++n) {
          bf16x8 b = *reinterpret_cast<const bf16x8*>(
              peu1 + (((size_t)(h * 8 + wid * 2 + n) * 6 + ks) * 64 + lane) * 8);
#pragma unroll
          for (int m = 0; m < 4; ++m) acc[m][n] = mfma16(a[m], b, acc[m][n]);
        }
      }
#pragma unroll
      for (int n = 0; n < 2; ++n) {
        const int col_l = wid * 32 + n * 16 + arow;
        const float bias = beu1[h * 128 + col_l];
#pragma unroll
        for (int m = 0; m < 4; ++m)
#pragma unroll
          for (int r = 0; r < 4; ++r) {
            float v = acc[m][n][r] + bias;
            act[m * 16 + r0 + r][col_l] = f2bf(v > 0.f ? v : 0.f);
          }
      }
    }
    __syncthreads();  // S6 / S8
    {  // GEMM4 partial: acc4 += a2_half @ w_eu2_half
      const int mrow = wid * 16 + arow;
#pragma unroll
      for (int ksl = 0; ksl < 4; ++ksl) {
        bf16x8 a = *reinterpret_cast<const bf16x8*>(&act[mrow][ksl * 32 + koff]);
#pragma unroll
        for (int n = 0; n < 4; ++n) {
          bf16x8 b = *reinterpret_cast<const bf16x8*>(
              peu2 + (((size_t)(n * 8 + h * 4 + ksl)) * 64 + lane) * 8);
          acc4[n] = mfma16(a, b, acc4[n]);
        }
      }
    }
    if (h == 0) __syncthreads();  // S7
  }

  // ---- epilogue: he_new = he + a2@w_eu2 + b; write out + atomic scatter ----
#pragma unroll
  for (int r = 0; r < 4; ++r) {
    const int erow = wid * 16 + r0 + r;
    const int eg = eb + erow;
    const float nv = nrm[eg];
    const int dn = edst[eg];
#pragma unroll
    for (int n = 0; n < 4; ++n) {
      const int col = n * 16 + arow;
      float v = acc4[n][r] + beu2[col] + bf2f(xa[erow][col]);
      out_he[(size_t)eg * 64 + col] = v;
      atomicAdd(nf + (size_t)dn * 64 + col, v * nv);
    }
  }
}

// Node MLP: hn_new = hn + relu([hn|node_ftr]@w_nl1+b)@w_nl2+b
__global__ __launch_bounds__(256, 3) void node_kernel(
    const float* __restrict__ hn, const float* __restrict__ nf,
    const unsigned short* __restrict__ pnl1, const float* __restrict__ bnl1,
    const unsigned short* __restrict__ pnl2, const float* __restrict__ bnl2,
    float* __restrict__ out) {
  __shared__ unsigned short xn[64][136];   // [hn | node_ftr]
  __shared__ unsigned short act[64][264];
  const int tid = threadIdx.x, lane = tid & 63, wid = tid >> 6;
  const int nb = blockIdx.x * 64;
  const int arow = lane & 15, koff = (lane >> 4) << 3, r0 = (lane >> 4) << 2;
  {
    const int rrow = tid >> 2, q = tid & 3, cg = q << 4;
    const int g = nb + rrow;
    if (g < NNODES) {
      const float4* aP = reinterpret_cast<const float4*>(hn + (size_t)g * 64 + cg);
      const float4* bP = reinterpret_cast<const float4*>(nf + (size_t)g * 64 + cg);
#pragma unroll
      for (int i = 0; i < 4; ++i) {
        float4 a = aP[i], b = bP[i];
        *reinterpret_cast<ushort4*>(&xn[rrow][cg + i * 4]) =
            make_ushort4(f2bf(a.x), f2bf(a.y), f2bf(a.z), f2bf(a.w));
        *reinterpret_cast<ushort4*>(&xn[rrow][64 + cg + i * 4]) =
            make_ushort4(f2bf(b.x), f2bf(b.y), f2bf(b.z), f2bf(b.w));
      }
    } else {
      ushort4 z = make_ushort4(0, 0, 0, 0);
#pragma unroll
      for (int i = 0; i < 4; ++i) {
        *reinterpret_cast<ushort4*>(&xn[rrow][cg + i * 4]) = z;
        *reinterpret_cast<ushort4*>(&xn[rrow][64 + cg + i * 4]) = z;
      }
    }
  }
  __syncthreads();
  {
    f32x4 acc[4][4];
#pragma unroll
    for (int m = 0; m < 4; ++m)
#pragma unroll
      for (int n = 0; n < 4; ++n) acc[m][n] = (f32x4){0.f, 0.f, 0.f, 0.f};
#pragma unroll
    for (int ks = 0; ks < 4; ++ks) {
      bf16x8 a[4];
#pragma unroll
      for (int m = 0; m < 4; ++m)
        a[m] = *reinterpret_cast<const bf16x8*>(&xn[m * 16 + arow][ks * 32 + koff]);
#pragma unroll
      for (int n = 0; n < 4; ++n) {
        bf16x8 b = *reinterpret_cast<const bf16x8*>(
            pnl1 + (((size_t)(wid * 4 + n) * 4 + ks) * 64 + lane) * 8);
#pragma unroll
        for (int m = 0; m < 4; ++m) acc[m][n] = mfma16(a[m], b, acc[m][n]);
      }
    }
#pragma unroll
    for (int n = 0; n < 4; ++n) {
      const int col = wid * 64 + n * 16 + arow;
      const float bias = bnl1[col];
#pragma unroll
      for (int m = 0; m < 4; ++m)
#pragma unroll
        for (int r = 0; r < 4; ++r) {
          float v = acc[m][n][r] + bias;
          act[m * 16 + r0 + r][col] = f2bf(v > 0.f ? v : 0.f);
        }
    }
  }
  __syncthreads();
  {
    f32x4 acc[4];
#pragma unroll
    for (int n = 0; n < 4; ++n) acc[n] = (f32x4){0.f, 0.f, 0.f, 0.f};
    const int mrow = wid * 16 + arow;
#pragma unroll
    for (int ks = 0; ks < 8; ++ks) {
      bf16x8 a = *reinterpret_cast<const bf16x8*>(&act[mrow][ks * 32 + koff]);
#pragma unroll
      for (int n = 0; n < 4; ++n) {
        bf16x8 b = *reinterpret_cast<const bf16x8*>(pnl2 + (((size_t)n * 8 + ks) * 64 + lane) * 8);
        acc[n] = mfma16(a, b, acc[n]);
      }
    }
#pragma unroll
    for (int r = 0; r < 4; ++r) {
      const int row = wid * 16 + r0 + r;
      const int g = nb + row;
      if (g < NNODES) {
#pragma unroll
        for (int n = 0; n < 4; ++n) {
          const int col = n * 16 + arow;
          out[(size_t)g * 64 + col] = bf2f(xn[row][col]) + acc[n][r] + bnl2[col];
        }
      }
    }
  }
}

extern "C" void kernel_launch(void* const* d_in, const int* in_sizes, int n_in,
                              void* d_out, int out_size, void* d_ws, size_t ws_size,
                              hipStream_t stream) {
  const float* hn   = (const float*)d_in[0];
  const float* he   = (const float*)d_in[1];
  const float* fe   = (const float*)d_in[2];
  const float* fes  = (const float*)d_in[3];
  const float* nrm  = (const float*)d_in[4];
  const int*   esrc = (const int*)d_in[5];
  const int*   edst = (const int*)d_in[6];
  const float* w_ev1 = (const float*)d_in[7];  const float* b_ev1 = (const float*)d_in[8];
  const float* w_ev2 = (const float*)d_in[9];  const float* b_ev2 = (const float*)d_in[10];
  const float* w_tp  = (const float*)d_in[11]; const float* b_tp  = (const float*)d_in[12];
  const float* w_eu1 = (const float*)d_in[13]; const float* b_eu1 = (const float*)d_in[14];
  const float* w_eu2 = (const float*)d_in[15]; const float* b_eu2 = (const float*)d_in[16];
  const float* w_nl1 = (const float*)d_in[17]; const float* b_nl1 = (const float*)d_in[18];
  const float* w_nl2 = (const float*)d_in[19]; const float* b_nl2 = (const float*)d_in[20];

  float* out = (float*)d_out;
  char* ws = (char*)d_ws;
  float* nf = (float*)ws;                                   // node_ftr accumulator [N,64] f32
  size_t off = (size_t)NNODES * CDIM * sizeof(float);
  unsigned short* pev1 = (unsigned short*)(ws + off); off += (size_t)16 * 6 * 512 * 2;
  unsigned short* peu1 = (unsigned short*)(ws + off); off += (size_t)16 * 6 * 512 * 2;
  unsigned short* pev2 = (unsigned short*)(ws + off); off += (size_t)1 * 8 * 512 * 2;
  unsigned short* peu2 = (unsigned short*)(ws + off); off += (size_t)4 * 8 * 512 * 2;
  unsigned short* ptp  = (unsigned short*)(ws + off); off += (size_t)4 * 2 * 512 * 2;
  unsigned short* pnl1 = (unsigned short*)(ws + off); off += (size_t)16 * 4 * 512 * 2;
  unsigned short* pnl2 = (unsigned short*)(ws + off); off += (size_t)4 * 8 * 512 * 2;

  hipMemsetAsync(nf, 0, (size_t)NNODES * CDIM * sizeof(float), stream);

  pack_all_kernel<<<84, 256, 0, stream>>>(
      w_ev1, w_eu1, w_nl1, w_eu2, w_nl2, w_ev2, w_tp,
      pev1, peu1, pnl1, peu2, pnl2, pev2, ptp);

  edge_kernel<<<NEDGES / 64, 256, 0, stream>>>(
      hn, he, fe, fes, nrm, esrc, edst,
      pev1, b_ev1, pev2, b_ev2, ptp, b_tp, peu1, b_eu1, peu2, b_eu2,
      out + (size_t)NNODES * CDIM, nf);

  node_kernel<<<(NNODES + 63) / 64, 256, 0, stream>>>(
      hn, nf, pnl1, b_nl1, pnl2, b_nl2, out);
}